// Round 5
// baseline (258.360 us; speedup 1.0000x reference)
//
#include <hip/hip_runtime.h>
#include <math.h>

#define B 8
#define NPTS 4096
#define THREADS 256
#define QPT 8                    // queries per thread in chamfer
#define NGRP 32                  // (dir=2) * (b=8) * (q-halves=2)
#define CTRL_BYTES 264           // words 0..65 zeroed each launch

// ws layout: [partial: 2*B*S*NPTS f][ctrl]
// ctrl (floats): [0..31] sums (dir*B+b)*2+{min,soft}
//                [32..63] group counters (u32)
//                [64] mlp counter (u32)   [65] final counter (u32)
//                [66..73] nlls[8]         [80..2127] h1buf[8*256]

__device__ __forceinline__ float min3f(float a, float b, float c) {
  return fminf(fminf(a, b), c);   // fuses to v_min3_f32
}

__device__ void final_combine(const float* sums, const float* nlls,
                              const float* __restrict__ wgt,
                              float* __restrict__ out) {
  volatile const float* vs = sums;
  volatile const float* vn = nlls;
  float chamfer = 0.f, prec = 0.f, rec = 0.f, dsw = 0.f, dom = 0.f;
  for (int bb = 0; bb < B; ++bb) {
    float sa  = vs[(0 * B + bb) * 2 + 0];
    float ssa = vs[(0 * B + bb) * 2 + 1];
    float sb  = vs[(1 * B + bb) * 2 + 0];
    float ssb = vs[(1 * B + bb) * 2 + 1];
    float ma = sa / 4096.f, mb = sb / 4096.f;
    float p = ssa / 4096.f, r = ssb / 4096.f;
    chamfer += ma + mb;
    prec += p; rec += r;
    float f_i = 2.f * p * r / (p + r + 1e-8f);
    float loss_i = ma + mb + 0.1f * (1.f - f_i);
    dsw += wgt[bb] * loss_i;
    dom += vn[bb];
  }
  chamfer *= (1.f / B); prec *= (1.f / B); rec *= (1.f / B);
  dsw *= (1.f / B); dom *= (1.f / B);
  float fscore = 2.f * prec * rec / (prec + rec + 1e-8f);
  float task = chamfer + 0.1f * (1.f - fscore);
  out[0] = 1.0f * task + 0.1f * dom + dsw;
}

template<int S, int LOG2S>
__global__ __launch_bounds__(THREADS, 4) void fused(
    const float* __restrict__ pred, const float* __restrict__ targ,
    const float* __restrict__ x, const float* __restrict__ W1,
    const float* __restrict__ b1, const float* __restrict__ W2,
    const float* __restrict__ b2, const float* __restrict__ W3,
    const float* __restrict__ b3, const int* __restrict__ labels,
    const float* __restrict__ wgt, float* __restrict__ partial,
    float* __restrict__ ctrl, float* __restrict__ out) {
  constexpr int REFS = NPTS / S;
  const int tid = threadIdx.x;
  const int bid = blockIdx.x;

  float* sums = ctrl;
  unsigned* gcnt    = (unsigned*)(ctrl + 32);
  unsigned* mlp_cnt = (unsigned*)(ctrl + 64);
  unsigned* fin_cnt = (unsigned*)(ctrl + 65);
  float* nlls_g = ctrl + 66;
  float* h1buf  = ctrl + 80;

  __shared__ float4 refs[REFS];
  __shared__ float red[8];
  __shared__ unsigned sh_t;

  if (bid >= NGRP * S) {
    // ================= MLP rider blocks (32): layer-1 =================
    int mid = bid - NGRP * S;          // 0..31
    int mb = mid >> 2, jc = (mid & 3) << 6;
    __shared__ float xs[512];
    __shared__ float ph[256];
    xs[tid]       = x[mb * 512 + tid];
    xs[256 + tid] = x[mb * 512 + 256 + tid];
    __syncthreads();
    int kq = tid >> 6, jj = tid & 63, j = jc + jj;
    float acc = 0.f;
    const float* w1 = W1 + (size_t)(kq * 128) * 256 + j;
#pragma unroll 8
    for (int k = 0; k < 128; ++k)
      acc = fmaf(xs[kq * 128 + k], w1[(size_t)k * 256], acc);
    ph[jj * 4 + kq] = acc;
    __syncthreads();
    if (tid < 64) {
      float a = b1[jc + tid] + ph[tid * 4 + 0] + ph[tid * 4 + 1]
              + ph[tid * 4 + 2] + ph[tid * 4 + 3];
      h1buf[mb * 256 + jc + tid] = fmaxf(a, 0.f);
    }
    __threadfence();
    __syncthreads();
    if (tid == 0) sh_t = atomicAdd(mlp_cnt, 1u);
    __syncthreads();
    if (sh_t != 31u) return;
    // -------- MLP finisher: L2 + L3 + NLL --------
    __threadfence();
    __shared__ float h1s[2048];
    __shared__ float h2s[1024];
    __shared__ float lg[48];
    __shared__ float nl[8];
    for (int i = tid; i < 2048; i += THREADS)
      h1s[i] = ((volatile const float*)h1buf)[i];
    __syncthreads();
    {
      int jo = tid & 127, hb = tid >> 7;
      float a0 = b2[jo], a1 = a0, a2 = a0, a3 = a0;
      const float* w2 = W2 + jo;
      for (int k = 0; k < 256; ++k) {
        float w = w2[(size_t)k * 128];
        a0 = fmaf(h1s[(0 + hb) * 256 + k], w, a0);
        a1 = fmaf(h1s[(2 + hb) * 256 + k], w, a1);
        a2 = fmaf(h1s[(4 + hb) * 256 + k], w, a2);
        a3 = fmaf(h1s[(6 + hb) * 256 + k], w, a3);
      }
      h2s[(0 + hb) * 128 + jo] = fmaxf(a0, 0.f);
      h2s[(2 + hb) * 128 + jo] = fmaxf(a1, 0.f);
      h2s[(4 + hb) * 128 + jo] = fmaxf(a2, 0.f);
      h2s[(6 + hb) * 128 + jo] = fmaxf(a3, 0.f);
    }
    __syncthreads();
    if (tid < 48) {
      int bb = tid / 6, d = tid % 6;
      float acc3 = b3[d];
#pragma unroll 8
      for (int k = 0; k < 128; ++k)
        acc3 = fmaf(h2s[bb * 128 + k], W3[k * 6 + d], acc3);
      lg[tid] = acc3;
    }
    __syncthreads();
    if (tid < 8) {
      int bb = tid;
      float mx = lg[bb * 6];
      for (int d = 1; d < 6; ++d) mx = fmaxf(mx, lg[bb * 6 + d]);
      float se = 0.f;
      for (int d = 0; d < 6; ++d) se += __expf(lg[bb * 6 + d] - mx);
      int lab = labels[bb];
      nl[bb] = -(lg[bb * 6 + lab] - mx - __logf(se));
    }
    __syncthreads();
    if (tid < 8) nlls_g[tid] = nl[tid];
    __threadfence();
    __syncthreads();
    if (tid == 0) sh_t = atomicAdd(fin_cnt, 1u);
    __syncthreads();
    if (sh_t == NGRP && tid == 0) final_combine(sums, nlls_g, wgt, out);
    return;
  }

  // ================= chamfer blocks =================
  // XCD-bijective decode: the S split-blocks of one group share bid%8.
  int xcd = bid & 7;
  int spl = (bid >> 3) & (S - 1);
  int cs  = bid >> (3 + LOG2S);
  int g   = cs * 8 + xcd;              // 0..31
  int qc  = g & 1;
  int b   = (g >> 1) & 7;
  int dir = g >> 4;
  const float* qp = dir ? targ : pred;
  const float* rp = dir ? pred : targ;

  const float* rb = rp + ((size_t)b * NPTS + (size_t)spl * REFS) * 3;
  for (int i = tid; i < REFS; i += THREADS) {
    float xx = rb[i * 3 + 0], yy = rb[i * 3 + 1], zz = rb[i * 3 + 2];
    refs[i] = make_float4(xx, yy, zz, 0.5f * (xx * xx + yy * yy + zz * zz));
  }
  __syncthreads();

  const float* qb = qp + (size_t)b * NPTS * 3;
  int q0 = qc * (QPT * THREADS) + tid;
  float qx[QPT], qy[QPT], qz[QPT], vmin[QPT];
#pragma unroll
  for (int i = 0; i < QPT; ++i) {
    int q = q0 + i * THREADS;
    qx[i] = qb[q * 3 + 0];
    qy[i] = qb[q * 3 + 1];
    qz[i] = qb[q * 3 + 2];
    vmin[i] = 3.4e38f;
  }

  for (int jr = 0; jr < REFS; jr += 8) {
    float4 t[8];
#pragma unroll
    for (int u = 0; u < 8; ++u) t[u] = refs[jr + u];
#pragma unroll
    for (int i = 0; i < QPT; ++i) {
      float s[8];
#pragma unroll
      for (int u = 0; u < 8; ++u)
        s[u] = fmaf(-qx[i], t[u].x,
               fmaf(-qy[i], t[u].y, fmaf(-qz[i], t[u].z, t[u].w)));
      float m0 = min3f(s[0], s[1], s[2]);
      float m1 = min3f(s[3], s[4], s[5]);
      float m2 = min3f(s[6], s[7], m0);
      vmin[i] = min3f(m1, m2, vmin[i]);
    }
  }

  size_t base = (((size_t)dir * B + b) * S + spl) * NPTS;
#pragma unroll
  for (int i = 0; i < QPT; ++i) {
    float qn = fmaf(qx[i], qx[i], fmaf(qy[i], qy[i], qz[i] * qz[i]));
    partial[base + q0 + i * THREADS] = fmaf(2.f, vmin[i], qn);
  }

  // ---- group handshake: last split-block of the group reduces it
  __threadfence();
  __syncthreads();
  if (tid == 0) sh_t = atomicAdd(&gcnt[g], 1u);
  __syncthreads();
  if (sh_t != (unsigned)(S - 1)) return;

  __threadfence();
  {
    const volatile float* vp = (const volatile float*)partial;
    size_t pb = ((size_t)dir * B + b) * S * NPTS;
    float s_min = 0.f, s_soft = 0.f;
    for (int i = 0; i < QPT; ++i) {
      int q = q0 + i * THREADS;
      float v[S];
#pragma unroll
      for (int s = 0; s < S; ++s)
        v[s] = vp[pb + (size_t)s * NPTS + q];
      float m = v[0];
#pragma unroll
      for (int s = 1; s < S; ++s) m = fminf(m, v[s]);
      s_min += m;
      s_soft += __expf(-5000.0f * m);   // 1/(2*sigma^2) = 5000
    }
    for (int off = 32; off > 0; off >>= 1) {
      s_min  += __shfl_down(s_min,  off);
      s_soft += __shfl_down(s_soft, off);
    }
    int wave = tid >> 6, lane = tid & 63;
    if (lane == 0) { red[wave * 2] = s_min; red[wave * 2 + 1] = s_soft; }
    __syncthreads();
    if (tid == 0) {
      float a = 0.f, c = 0.f;
      for (int wv = 0; wv < 4; ++wv) { a += red[wv * 2]; c += red[wv * 2 + 1]; }
      atomicAdd(&sums[(dir * B + b) * 2 + 0], a);
      atomicAdd(&sums[(dir * B + b) * 2 + 1], c);
      __threadfence();
      sh_t = atomicAdd(fin_cnt, 1u);
    }
    __syncthreads();
    if (sh_t == NGRP) {   // saw all 32 groups + the MLP increment
      __threadfence();
      if (tid == 0) final_combine(sums, nlls_g, wgt, out);
    }
  }
}

// ======================= host dispatch ==================================
template<int S, int LOG2S>
static void run_pipeline(const float* pred, const float* targ, const float* x,
                         const float* wgt, const float* W1, const float* b1,
                         const float* W2, const float* b2, const float* W3,
                         const float* b3, const int* labels, float* out,
                         char* ws, hipStream_t stream) {
  float* partial = (float*)ws;
  float* ctrl    = partial + (size_t)2 * B * S * NPTS;

  hipMemsetAsync(ctrl, 0, CTRL_BYTES, stream);
  hipLaunchKernelGGL((fused<S, LOG2S>), dim3(NGRP * S + 32), dim3(THREADS),
                     0, stream, pred, targ, x, W1, b1, W2, b2, W3, b3,
                     labels, wgt, partial, ctrl, out);
}

extern "C" void kernel_launch(void* const* d_in, const int* in_sizes, int n_in,
                              void* d_out, int out_size, void* d_ws, size_t ws_size,
                              hipStream_t stream) {
  const float* pred   = (const float*)d_in[0];
  const float* targ   = (const float*)d_in[1];
  const float* x      = (const float*)d_in[2];
  const float* wgt    = (const float*)d_in[3];
  const float* W1     = (const float*)d_in[4];
  const float* b1     = (const float*)d_in[5];
  const float* W2     = (const float*)d_in[6];
  const float* b2     = (const float*)d_in[7];
  const float* W3     = (const float*)d_in[8];
  const float* b3     = (const float*)d_in[9];
  const int*   labels = (const int*)d_in[10];
  float* out = (float*)d_out;
  char* ws = (char*)d_ws;

  auto need = [](int S) {
    return ((size_t)2 * B * S * NPTS + 80 + 2048) * sizeof(float);
  };
  if (ws_size >= need(32))
    run_pipeline<32, 5>(pred, targ, x, wgt, W1, b1, W2, b2, W3, b3, labels,
                        out, ws, stream);
  else if (ws_size >= need(16))
    run_pipeline<16, 4>(pred, targ, x, wgt, W1, b1, W2, b2, W3, b3, labels,
                        out, ws, stream);
  else
    run_pipeline<8, 3>(pred, targ, x, wgt, W1, b1, W2, b2, W3, b3, labels,
                       out, ws, stream);
}

// Round 6
// 131.667 us; speedup vs baseline: 1.9622x; 1.9622x over previous
//
#include <hip/hip_runtime.h>
#include <math.h>

#define B 8
#define NPTS 4096
#define QPT 8           // queries per thread in chamfer
#define THREADS 256
#define NGRP 32         // (dir=2) * (b=8) * (q-halves=2)

__device__ __forceinline__ float min3f(float a, float b, float c) {
  return fminf(fminf(a, b), c);   // fuses to v_min3_f32
}

// ws layout: [partial: 2*B*S*NPTS f][sums64: 64 f][h1p: 64*256 f][h2p: 16*128 f]
// partial[((dir*B+b)*S + split)*NPTS + q]
// sums64[(dir*B+b)*2 + {0:min,1:soft}]; sums64[32] = k2 done-counter (u32)

// ======== K1: 64 MLP-L1 blocks + NGRP*S chamfer blocks. NO fences. =========
template<int S, int LOG2S>
__global__ __launch_bounds__(THREADS, 4) void k1_kernel(
    const float* __restrict__ pred, const float* __restrict__ targ,
    const float* __restrict__ x, const float* __restrict__ W1,
    float* __restrict__ partial, float* __restrict__ sums64,
    float* __restrict__ h1p) {
  constexpr int REFS = NPTS / S;   // 256 for S=16
  const int tid = threadIdx.x;
  const int id = blockIdx.x;

  __shared__ float4 refs[REFS];
  __shared__ float xs[64];

  if (id < 64) {
    // MLP layer-1 partials: h1p[(b*8+kc)*256+j] = sum_{k in chunk} x[b,k]W1[k,j]
    if (id == 0 && tid < 64) sums64[tid] = 0.f;   // zero sums + done-counter
    int b = id >> 3, kc = id & 7;
    if (tid < 64) xs[tid] = x[b * 512 + kc * 64 + tid];
    __syncthreads();
    float acc = 0.f;
    const float* w = W1 + (size_t)(kc * 64) * 256 + tid;
#pragma unroll 8
    for (int k = 0; k < 64; ++k) acc = fmaf(xs[k], w[k * 256], acc);
    h1p[(b * 8 + kc) * 256 + tid] = acc;
    return;
  }

  // ---- chamfer: one (dir,b,qhalf,split) slice per block
  int cid = id - 64;
  int spl = cid & (S - 1);
  int g   = cid >> LOG2S;          // 0..31
  int qc  = g & 1;
  int b   = (g >> 1) & 7;
  int dir = g >> 4;
  const float* qp = dir ? targ : pred;
  const float* rp = dir ? pred : targ;

  const float* rb = rp + ((size_t)b * NPTS + (size_t)spl * REFS) * 3;
  for (int i = tid; i < REFS; i += THREADS) {
    float xx = rb[i * 3 + 0], yy = rb[i * 3 + 1], zz = rb[i * 3 + 2];
    refs[i] = make_float4(xx, yy, zz, 0.5f * (xx * xx + yy * yy + zz * zz));
  }
  __syncthreads();

  const float* qb = qp + (size_t)b * NPTS * 3;
  int q0 = qc * (QPT * THREADS) + tid;
  float qx[QPT], qy[QPT], qz[QPT], vmin[QPT];
#pragma unroll
  for (int i = 0; i < QPT; ++i) {
    int q = q0 + i * THREADS;
    qx[i] = qb[q * 3 + 0];
    qy[i] = qb[q * 3 + 1];
    qz[i] = qb[q * 3 + 2];
    vmin[i] = 3.4e38f;
  }

  for (int jr = 0; jr < REFS; jr += 8) {
    float4 t[8];
#pragma unroll
    for (int u = 0; u < 8; ++u) t[u] = refs[jr + u];
#pragma unroll
    for (int i = 0; i < QPT; ++i) {
      float s[8];
#pragma unroll
      for (int u = 0; u < 8; ++u)
        s[u] = fmaf(-qx[i], t[u].x,
               fmaf(-qy[i], t[u].y, fmaf(-qz[i], t[u].z, t[u].w)));
      float m0 = min3f(s[0], s[1], s[2]);
      float m1 = min3f(s[3], s[4], s[5]);
      float m2 = min3f(s[6], s[7], m0);
      vmin[i] = min3f(m1, m2, vmin[i]);
    }
  }

  size_t base = (((size_t)dir * B + b) * S + spl) * NPTS;
#pragma unroll
  for (int i = 0; i < QPT; ++i) {
    float qn = fmaf(qx[i], qx[i], fmaf(qy[i], qy[i], qz[i] * qz[i]));
    partial[base + q0 + i * THREADS] = fmaf(2.f, vmin[i], qn);
  }
}

// ======== K2: 256 reduce blocks + 16 MLP-L2 blocks; last block -> final ====
template<int S>
__global__ __launch_bounds__(THREADS) void k2_kernel(
    const float* __restrict__ partial, float* __restrict__ sums64,
    const float* __restrict__ h1p, const float* __restrict__ b1,
    const float* __restrict__ W2, const float* __restrict__ b2,
    const float* __restrict__ W3, const float* __restrict__ b3,
    const int* __restrict__ labels, const float* __restrict__ wgt,
    float* __restrict__ out) {
  constexpr int NBLK = 272;
  const int id = blockIdx.x;
  const int tid = threadIdx.x;
  __shared__ float red[8];
  __shared__ float hs[128];
  __shared__ bool is_last;

  if (id >= 256) {
    // ---- MLP-L2 partials: h2p[(b*2+half)*128+j] over k in [half*128,+128)
    int lid = id - 256;
    int b = lid >> 1, half = lid & 1;
    if (tid < 128) {
      int k = half * 128 + tid;
      float a = b1[k];
#pragma unroll
      for (int p = 0; p < 8; ++p) a += h1p[(b * 8 + p) * 256 + k];
      hs[tid] = fmaxf(a, 0.f);
    }
    __syncthreads();
    if (tid < 128) {
      float acc = 0.f;
      const float* w = W2 + (size_t)(half * 128) * 128 + tid;
#pragma unroll 8
      for (int k = 0; k < 128; ++k) acc = fmaf(hs[k], w[k * 128], acc);
      float* h2p = sums64 + 64 + 64 * 256;
      h2p[(b * 2 + half) * 128 + tid] = acc;
    }
  } else {
    // ---- reduce: min over S splits (batched loads), sum min and exp
    int chunk = id & 15;
    int b   = (id >> 4) & 7;
    int dir = id >> 7;
    size_t pb = ((size_t)dir * B + b) * S * NPTS;
    int q = chunk * 256 + tid;

    float v[S];
#pragma unroll
    for (int s = 0; s < S; ++s)
      v[s] = partial[pb + (size_t)s * NPTS + q];
    float m = v[0];
#pragma unroll
    for (int s = 1; s < S; ++s) m = fminf(m, v[s]);
    float s_min = m;
    float s_soft = __expf(-5000.0f * m);   // 1/(2*sigma^2) = 5000

    for (int off = 32; off > 0; off >>= 1) {
      s_min  += __shfl_down(s_min,  off);
      s_soft += __shfl_down(s_soft, off);
    }
    int wave = tid >> 6, lane = tid & 63;
    if (lane == 0) { red[wave * 2] = s_min; red[wave * 2 + 1] = s_soft; }
    __syncthreads();
    if (tid == 0) {
      float a = 0.f, c = 0.f;
      for (int wv = 0; wv < 4; ++wv) { a += red[wv * 2]; c += red[wv * 2 + 1]; }
      atomicAdd(&sums64[(dir * B + b) * 2 + 0], a);
      atomicAdd(&sums64[(dir * B + b) * 2 + 1], c);
    }
  }

  // ---- done-counter handshake (stores -> fence -> sync -> counter)
  __threadfence();
  __syncthreads();
  if (tid == 0) {
    unsigned t = atomicAdd((unsigned*)(sums64 + 32), 1u);
    is_last = (t == NBLK - 1);
  }
  __syncthreads();
  if (!is_last) return;
  __threadfence();                                   // acquire side

  // ---- tail (last block): L2-combine + L3 + softmax/NLL + final combine
  __shared__ float h2s[8 * 128];
  __shared__ float lg[48];
  __shared__ float nlls[8];
  volatile const float* vh2 = (volatile const float*)(sums64 + 64 + 64 * 256);

  for (int i = tid; i < 1024; i += THREADS) {
    int bb = i >> 7, j = i & 127;
    float a = b2[j] + vh2[(bb * 2 + 0) * 128 + j] + vh2[(bb * 2 + 1) * 128 + j];
    h2s[i] = fmaxf(a, 0.f);
  }
  __syncthreads();
  if (tid < 48) {
    int bb = tid / 6, d = tid % 6;
    float acc = b3[d];
#pragma unroll 8
    for (int k = 0; k < 128; ++k)
      acc = fmaf(h2s[bb * 128 + k], W3[k * 6 + d], acc);
    lg[tid] = acc;
  }
  __syncthreads();
  if (tid < 8) {
    int bb = tid;
    float mx = lg[bb * 6];
    for (int d = 1; d < 6; ++d) mx = fmaxf(mx, lg[bb * 6 + d]);
    float se = 0.f;
    for (int d = 0; d < 6; ++d) se += __expf(lg[bb * 6 + d] - mx);
    int lab = labels[bb];
    nlls[bb] = -(lg[bb * 6 + lab] - mx - __logf(se));
  }
  __syncthreads();
  if (tid == 0) {
    volatile const float* vs = (volatile const float*)sums64;
    float chamfer = 0.f, prec = 0.f, rec = 0.f, dsw = 0.f, dom = 0.f;
    for (int bb = 0; bb < B; ++bb) {
      float sa  = vs[(0 * B + bb) * 2 + 0];
      float ssa = vs[(0 * B + bb) * 2 + 1];
      float sb  = vs[(1 * B + bb) * 2 + 0];
      float ssb = vs[(1 * B + bb) * 2 + 1];
      float ma = sa / 4096.f, mb = sb / 4096.f;
      float p = ssa / 4096.f, r = ssb / 4096.f;
      chamfer += ma + mb;
      prec += p; rec += r;
      float f_i = 2.f * p * r / (p + r + 1e-8f);
      float loss_i = ma + mb + 0.1f * (1.f - f_i);
      dsw += wgt[bb] * loss_i;
      dom += nlls[bb];
    }
    chamfer *= (1.f / B); prec *= (1.f / B); rec *= (1.f / B);
    dsw *= (1.f / B); dom *= (1.f / B);
    float fscore = 2.f * prec * rec / (prec + rec + 1e-8f);
    float task = chamfer + 0.1f * (1.f - fscore);
    out[0] = 1.0f * task + 0.1f * dom + dsw;
  }
}

// ======================= host dispatch ==================================
template<int S, int LOG2S>
static void run_pipeline(const float* pred, const float* targ, const float* x,
                         const float* wgt, const float* W1, const float* b1,
                         const float* W2, const float* b2, const float* W3,
                         const float* b3, const int* labels, float* out,
                         char* ws, hipStream_t stream) {
  float* partial = (float*)ws;
  float* sums64  = partial + (size_t)2 * B * S * NPTS;
  float* h1p     = sums64 + 64;

  hipLaunchKernelGGL((k1_kernel<S, LOG2S>), dim3(64 + NGRP * S), dim3(THREADS),
                     0, stream, pred, targ, x, W1, partial, sums64, h1p);
  hipLaunchKernelGGL((k2_kernel<S>), dim3(272), dim3(THREADS), 0, stream,
                     partial, sums64, h1p, b1, W2, b2, W3, b3, labels, wgt,
                     out);
}

extern "C" void kernel_launch(void* const* d_in, const int* in_sizes, int n_in,
                              void* d_out, int out_size, void* d_ws, size_t ws_size,
                              hipStream_t stream) {
  const float* pred   = (const float*)d_in[0];
  const float* targ   = (const float*)d_in[1];
  const float* x      = (const float*)d_in[2];
  const float* wgt    = (const float*)d_in[3];
  const float* W1     = (const float*)d_in[4];
  const float* b1     = (const float*)d_in[5];
  const float* W2     = (const float*)d_in[6];
  const float* b2     = (const float*)d_in[7];
  const float* W3     = (const float*)d_in[8];
  const float* b3     = (const float*)d_in[9];
  const int*   labels = (const int*)d_in[10];
  float* out = (float*)d_out;
  char* ws = (char*)d_ws;

  auto need = [](int S) {
    return ((size_t)2 * B * S * NPTS + 64 + 64 * 256 + 16 * 128) * sizeof(float);
  };
  if (ws_size >= need(16))
    run_pipeline<16, 4>(pred, targ, x, wgt, W1, b1, W2, b2, W3, b3, labels,
                        out, ws, stream);
  else
    run_pipeline<8, 3>(pred, targ, x, wgt, W1, b1, W2, b2, W3, b3, labels,
                       out, ws, stream);
}

// Round 7
// 118.158 us; speedup vs baseline: 2.1866x; 1.1143x over previous
//
#include <hip/hip_runtime.h>
#include <math.h>

#define B 8
#define NPTS 4096
#define QPT 8           // queries per thread in chamfer
#define THREADS 256

__device__ __forceinline__ float min3f(float a, float b, float c) {
  return fminf(fminf(a, b), c);   // fuses to v_min3_f32
}

// ws layout: [partial: 2*B*S*NPTS f][sums64: 64 f][h1p: 64*256 f][h2p: 16*128 f]
// partial[((dir*B+b)*S + split)*NPTS + q]
// sums64[(dir*B+b)*2 + {0:min,1:soft}]; sums64[32] = k2 done-counter (u32)

// ======== K1: 64 MLP-L1 blocks + 32*S chamfer blocks (R0-proven, no fences)
template<int S, int LOG2S>
__global__ __launch_bounds__(THREADS, 4) void k1_kernel(
    const float* __restrict__ pred, const float* __restrict__ targ,
    const float* __restrict__ x, const float* __restrict__ W1,
    float* __restrict__ partial, float* __restrict__ sums64,
    float* __restrict__ h1p) {
  constexpr int REFS = NPTS / S;   // 128 for S=32
  const int id = blockIdx.x;
  const int tid = threadIdx.x;

  __shared__ float4 refs[REFS];
  __shared__ float xs[64];

  if (id < 64) {
    // MLP layer-1 partials: h1p[(b*8+kc)*256+j] = sum_k x[b,k]W1[k,j]
    if (id == 0 && tid < 64) sums64[tid] = 0.f;   // zero sums + done-counter
    int b = id >> 3, kc = id & 7;
    if (tid < 64) xs[tid] = x[b * 512 + kc * 64 + tid];
    __syncthreads();
    float acc = 0.f;
    const float* w = W1 + (size_t)(kc * 64) * 256 + tid;
#pragma unroll 8
    for (int k = 0; k < 64; ++k) acc = fmaf(xs[k], w[k * 256], acc);
    h1p[(b * 8 + kc) * 256 + tid] = acc;
    return;
  }

  // ---- chamfer split-partial mins
  int cid = id - 64;
  int split  = cid & (S - 1);
  int qchunk = (cid >> LOG2S) & 1;
  int b      = (cid >> (LOG2S + 1)) & 7;
  int dir    = cid >> (LOG2S + 4);
  const float* qp = dir ? targ : pred;
  const float* rp = dir ? pred : targ;

  const float* rb = rp + ((size_t)b * NPTS + (size_t)split * REFS) * 3;
  for (int i = tid; i < REFS; i += THREADS) {
    float xx = rb[i * 3 + 0], yy = rb[i * 3 + 1], zz = rb[i * 3 + 2];
    refs[i] = make_float4(xx, yy, zz, 0.5f * (xx * xx + yy * yy + zz * zz));
  }
  __syncthreads();

  const float* qb = qp + (size_t)b * NPTS * 3;
  int q0 = qchunk * (QPT * THREADS) + tid;
  float qx[QPT], qy[QPT], qz[QPT], vmin[QPT];
#pragma unroll
  for (int i = 0; i < QPT; ++i) {
    int q = q0 + i * THREADS;
    qx[i] = qb[q * 3 + 0];
    qy[i] = qb[q * 3 + 1];
    qz[i] = qb[q * 3 + 2];
    vmin[i] = 3.4e38f;
  }

  for (int j = 0; j < REFS; j += 8) {
    float4 t[8];
#pragma unroll
    for (int u = 0; u < 8; ++u) t[u] = refs[j + u];
#pragma unroll
    for (int i = 0; i < QPT; ++i) {
      float s[8];
#pragma unroll
      for (int u = 0; u < 8; ++u)
        s[u] = fmaf(-qx[i], t[u].x,
               fmaf(-qy[i], t[u].y, fmaf(-qz[i], t[u].z, t[u].w)));
      float m0 = min3f(s[0], s[1], s[2]);
      float m1 = min3f(s[3], s[4], s[5]);
      float m2 = min3f(s[6], s[7], m0);
      vmin[i] = min3f(m1, m2, vmin[i]);
    }
  }

  size_t base = (((size_t)dir * B + b) * S + split) * NPTS;
#pragma unroll
  for (int i = 0; i < QPT; ++i) {
    float qn = fmaf(qx[i], qx[i], fmaf(qy[i], qy[i], qz[i] * qz[i]));
    partial[base + q0 + i * THREADS] = fmaf(2.f, vmin[i], qn);
  }
}

// ======== K2: 256 reduce + 16 MLP-L2 blocks; fence-light last-block tail ===
// Reduce blocks emit ONLY atomics: sums-adds ordered before the counter-add
// by s_waitcnt vmcnt(0) (no L2 writeback). Only the 16 MLP blocks (normal
// stores) execute a release __threadfence; tail does one acquire fence.
template<int S>
__global__ __launch_bounds__(THREADS) void k2_kernel(
    const float* __restrict__ partial, float* __restrict__ sums64,
    const float* __restrict__ h1p, const float* __restrict__ b1,
    const float* __restrict__ W2, const float* __restrict__ b2,
    const float* __restrict__ W3, const float* __restrict__ b3,
    const int* __restrict__ labels, const float* __restrict__ wgt,
    float* __restrict__ out) {
  constexpr int NBLK = 272;
  const int id = blockIdx.x;
  const int tid = threadIdx.x;
  __shared__ float red[8];
  __shared__ float hs[128];
  __shared__ bool is_last;

  if (id >= 256) {
    // ---- MLP-L2 partials: h2p[(b*2+half)*128+j] over k in [half*128,+128)
    int lid = id - 256;
    int b = lid >> 1, half = lid & 1;
    if (tid < 128) {
      int k = half * 128 + tid;
      float a = b1[k];
#pragma unroll
      for (int p = 0; p < 8; ++p) a += h1p[(b * 8 + p) * 256 + k];
      hs[tid] = fmaxf(a, 0.f);
    }
    __syncthreads();
    if (tid < 128) {
      float acc = 0.f;
      const float* w = W2 + (size_t)(half * 128) * 128 + tid;
#pragma unroll 8
      for (int k = 0; k < 128; ++k) acc = fmaf(hs[k], w[k * 128], acc);
      float* h2p = sums64 + 64 + 64 * 256;
      h2p[(b * 2 + half) * 128 + tid] = acc;
    }
    __threadfence();          // release h2p stores (16 blocks only)
    __syncthreads();
    if (tid == 0) {
      unsigned t = atomicAdd((unsigned*)(sums64 + 32), 1u);
      is_last = (t == NBLK - 1);
    }
  } else {
    // ---- reduce: min over S splits (batched loads), sum min and exp
    int chunk = id & 15;
    int b   = (id >> 4) & 7;
    int dir = id >> 7;
    size_t pb = ((size_t)dir * B + b) * S * NPTS;
    int q = chunk * 256 + tid;

    float v[S];
#pragma unroll
    for (int s = 0; s < S; ++s)
      v[s] = partial[pb + (size_t)s * NPTS + q];
    float m = v[0];
#pragma unroll
    for (int s = 1; s < S; ++s) m = fminf(m, v[s]);
    float s_min = m;
    float s_soft = __expf(-5000.0f * m);   // 1/(2*sigma^2) = 5000

    for (int off = 32; off > 0; off >>= 1) {
      s_min  += __shfl_down(s_min,  off);
      s_soft += __shfl_down(s_soft, off);
    }
    int wave = tid >> 6, lane = tid & 63;
    if (lane == 0) { red[wave * 2] = s_min; red[wave * 2 + 1] = s_soft; }
    __syncthreads();
    if (tid == 0) {
      float a = 0.f, c = 0.f;
      for (int wv = 0; wv < 4; ++wv) { a += red[wv * 2]; c += red[wv * 2 + 1]; }
      atomicAdd(&sums64[(dir * B + b) * 2 + 0], a);
      atomicAdd(&sums64[(dir * B + b) * 2 + 1], c);
      // order the two sums-adds before the counter-add WITHOUT an L2
      // writeback: wait for their acks, then increment.
      asm volatile("s_waitcnt vmcnt(0)" ::: "memory");
      unsigned t = atomicAdd((unsigned*)(sums64 + 32), 1u);
      is_last = (t == NBLK - 1);
    }
  }
  __syncthreads();
  if (!is_last) return;
  __threadfence();                                   // acquire (1 block)

  // ---- tail (last block): L2-combine + L3 + softmax/NLL + final combine
  __shared__ float h2s[8 * 128];
  __shared__ float lg[48];
  __shared__ float nlls[8];
  volatile const float* vh2 = (volatile const float*)(sums64 + 64 + 64 * 256);

  for (int i = tid; i < 1024; i += THREADS) {
    int bb = i >> 7, j = i & 127;
    float a = b2[j] + vh2[(bb * 2 + 0) * 128 + j] + vh2[(bb * 2 + 1) * 128 + j];
    h2s[i] = fmaxf(a, 0.f);
  }
  __syncthreads();
  if (tid < 48) {
    int bb = tid / 6, d = tid % 6;
    float acc = b3[d];
#pragma unroll 8
    for (int k = 0; k < 128; ++k)
      acc = fmaf(h2s[bb * 128 + k], W3[k * 6 + d], acc);
    lg[tid] = acc;
  }
  __syncthreads();
  if (tid < 8) {
    int bb = tid;
    float mx = lg[bb * 6];
    for (int d = 1; d < 6; ++d) mx = fmaxf(mx, lg[bb * 6 + d]);
    float se = 0.f;
    for (int d = 0; d < 6; ++d) se += __expf(lg[bb * 6 + d] - mx);
    int lab = labels[bb];
    nlls[bb] = -(lg[bb * 6 + lab] - mx - __logf(se));
  }
  __syncthreads();
  if (tid == 0) {
    volatile const float* vs = (volatile const float*)sums64;
    float chamfer = 0.f, prec = 0.f, rec = 0.f, dsw = 0.f, dom = 0.f;
    for (int bb = 0; bb < B; ++bb) {
      float sa  = vs[(0 * B + bb) * 2 + 0];
      float ssa = vs[(0 * B + bb) * 2 + 1];
      float sb  = vs[(1 * B + bb) * 2 + 0];
      float ssb = vs[(1 * B + bb) * 2 + 1];
      float ma = sa / 4096.f, mb = sb / 4096.f;
      float p = ssa / 4096.f, r = ssb / 4096.f;
      chamfer += ma + mb;
      prec += p; rec += r;
      float f_i = 2.f * p * r / (p + r + 1e-8f);
      float loss_i = ma + mb + 0.1f * (1.f - f_i);
      dsw += wgt[bb] * loss_i;
      dom += nlls[bb];
    }
    chamfer *= (1.f / B); prec *= (1.f / B); rec *= (1.f / B);
    dsw *= (1.f / B); dom *= (1.f / B);
    float fscore = 2.f * prec * rec / (prec + rec + 1e-8f);
    float task = chamfer + 0.1f * (1.f - fscore);
    out[0] = 1.0f * task + 0.1f * dom + dsw;
  }
}

// ======================= host dispatch ==================================
template<int S, int LOG2S>
static void run_pipeline(const float* pred, const float* targ, const float* x,
                         const float* wgt, const float* W1, const float* b1,
                         const float* W2, const float* b2, const float* W3,
                         const float* b3, const int* labels, float* out,
                         char* ws, hipStream_t stream) {
  float* partial = (float*)ws;
  float* sums64  = partial + (size_t)2 * B * S * NPTS;
  float* h1p     = sums64 + 64;

  hipLaunchKernelGGL((k1_kernel<S, LOG2S>), dim3(64 + 32 * S), dim3(THREADS),
                     0, stream, pred, targ, x, W1, partial, sums64, h1p);
  hipLaunchKernelGGL((k2_kernel<S>), dim3(272), dim3(THREADS), 0, stream,
                     partial, sums64, h1p, b1, W2, b2, W3, b3, labels, wgt,
                     out);
}

extern "C" void kernel_launch(void* const* d_in, const int* in_sizes, int n_in,
                              void* d_out, int out_size, void* d_ws, size_t ws_size,
                              hipStream_t stream) {
  const float* pred   = (const float*)d_in[0];
  const float* targ   = (const float*)d_in[1];
  const float* x      = (const float*)d_in[2];
  const float* wgt    = (const float*)d_in[3];
  const float* W1     = (const float*)d_in[4];
  const float* b1     = (const float*)d_in[5];
  const float* W2     = (const float*)d_in[6];
  const float* b2     = (const float*)d_in[7];
  const float* W3     = (const float*)d_in[8];
  const float* b3     = (const float*)d_in[9];
  const int*   labels = (const int*)d_in[10];
  float* out = (float*)d_out;
  char* ws = (char*)d_ws;

  auto need = [](int S) {
    return ((size_t)2 * B * S * NPTS + 64 + 64 * 256 + 16 * 128) * sizeof(float);
  };
  if (ws_size >= need(32))
    run_pipeline<32, 5>(pred, targ, x, wgt, W1, b1, W2, b2, W3, b3, labels,
                        out, ws, stream);
  else if (ws_size >= need(16))
    run_pipeline<16, 4>(pred, targ, x, wgt, W1, b1, W2, b2, W3, b3, labels,
                        out, ws, stream);
  else
    run_pipeline<8, 3>(pred, targ, x, wgt, W1, b1, W2, b2, W3, b3, labels,
                       out, ws, stream);
}